// Round 1
// baseline (338.183 us; speedup 1.0000x reference)
//
#include <hip/hip_runtime.h>
#include <math.h>

// Problem constants (fixed by setup_inputs)
#define B  32
#define C  192
#define CS 48      // C / N_SPLIT
#define T  8192
#define TV 2048    // T / 4 (float4 elements along t)

__device__ __forceinline__ float4 fma4(float s, float4 v, float4 acc) {
    acc.x += s * v.x; acc.y += s * v.y; acc.z += s * v.z; acc.w += s * v.w;
    return acc;
}

// z[b, c, t]: for each (b, j, t), channels {2j, 2j+1, 96+2j, 96+2j+1}
// (split index n = 2g + k for c = 96g + 2j + k) mixed by 4x4 W, times mask.
__global__ __launch_bounds__(256) void invconv_z(
    const float4* __restrict__ x, const float4* __restrict__ mask,
    const float* __restrict__ w, float4* __restrict__ out)
{
    int gid = blockIdx.x * 256 + threadIdx.x;   // [0, B*CS*TV)
    int tv  = gid & (TV - 1);
    int bj  = gid >> 11;                        // / TV
    int j   = bj % CS;
    int b   = bj / CS;

    // Uniform weight load (same address across wave -> broadcast via L1)
    float wr[16];
#pragma unroll
    for (int i = 0; i < 16; ++i) wr[i] = w[i];

    long base = (long)b * C * TV;
    int  c0   = 2 * j;         // n = 0
    int  c2   = 96 + 2 * j;    // n = 2

    float4 a[4];
    a[0] = x[base + (long)(c0    ) * TV + tv];
    a[1] = x[base + (long)(c0 + 1) * TV + tv];
    a[2] = x[base + (long)(c2    ) * TV + tv];
    a[3] = x[base + (long)(c2 + 1) * TV + tv];
    float4 m = mask[(long)b * TV + tv];

    int cout[4] = { c0, c0 + 1, c2, c2 + 1 };
#pragma unroll
    for (int i = 0; i < 4; ++i) {
        float4 o = make_float4(0.f, 0.f, 0.f, 0.f);
#pragma unroll
        for (int n = 0; n < 4; ++n) o = fma4(wr[i * 4 + n], a[n], o);
        o.x *= m.x; o.y *= m.y; o.z *= m.z; o.w *= m.w;
        out[base + (long)cout[i] * TV + tv] = o;
    }
}

// logdet[b] = log|det(W)| * (C/N_SPLIT) * sum(mask[b])
__global__ __launch_bounds__(256) void invconv_logdet(
    const float* __restrict__ mask, const float* __restrict__ w,
    float* __restrict__ ld)
{
    int b = blockIdx.x;
    float s = 0.f;
    for (int t = threadIdx.x; t < T; t += 256) s += mask[(long)b * T + t];
#pragma unroll
    for (int off = 32; off; off >>= 1) s += __shfl_down(s, off, 64);

    __shared__ float partial[4];
    int lane = threadIdx.x & 63, wv = threadIdx.x >> 6;
    if (lane == 0) partial[wv] = s;
    __syncthreads();

    if (threadIdx.x == 0) {
        float xlen = partial[0] + partial[1] + partial[2] + partial[3];
        double a[16];
#pragma unroll
        for (int i = 0; i < 16; ++i) a[i] = (double)w[i];
        // det(4x4) via 2x2-block cofactors (double precision: W ~ orthogonal,
        // log|det| ~ 0 gets amplified by 48*8192 -> need accuracy here)
        double s0 = a[0]*a[5]  - a[1]*a[4];
        double s1 = a[0]*a[6]  - a[2]*a[4];
        double s2 = a[0]*a[7]  - a[3]*a[4];
        double s3 = a[1]*a[6]  - a[2]*a[5];
        double s4 = a[1]*a[7]  - a[3]*a[5];
        double s5 = a[2]*a[7]  - a[3]*a[6];
        double c5 = a[10]*a[15] - a[11]*a[14];
        double c4 = a[9]*a[15]  - a[11]*a[13];
        double c3 = a[9]*a[14]  - a[10]*a[13];
        double c2 = a[8]*a[15]  - a[11]*a[12];
        double c1 = a[8]*a[14]  - a[10]*a[12];
        double c0 = a[8]*a[13]  - a[9]*a[12];
        double det = s0*c5 - s1*c4 + s2*c3 + s3*c2 - s4*c1 + s5*c0;
        ld[b] = (float)(log(fabs(det)) * (double)(C / 4) * (double)xlen);
    }
}

extern "C" void kernel_launch(void* const* d_in, const int* in_sizes, int n_in,
                              void* d_out, int out_size, void* d_ws, size_t ws_size,
                              hipStream_t stream) {
    const float* x    = (const float*)d_in[0];   // (32, 192, 8192) fp32
    const float* mask = (const float*)d_in[1];   // (32, 1, 8192) fp32
    const float* w    = (const float*)d_in[2];   // (4, 4) fp32
    float* z  = (float*)d_out;                           // 32*192*8192
    float* ld = (float*)d_out + (size_t)B * C * T;       // +32

    int total = B * CS * TV;                     // 3,145,728 threads
    invconv_z<<<total / 256, 256, 0, stream>>>(
        (const float4*)x, (const float4*)mask, w, (float4*)z);
    invconv_logdet<<<B, 256, 0, stream>>>(mask, w, ld);
}

// Round 2
// 326.519 us; speedup vs baseline: 1.0357x; 1.0357x over previous
//
#include <hip/hip_runtime.h>
#include <math.h>

// Problem constants (fixed by setup_inputs)
#define B   32
#define C   192
#define CS  48      // C / N_SPLIT
#define T   8192
#define TV  2048    // T / 4  (float4 elements along t)
#define TVH 1024    // TV / 2 (each thread does tv and tv+TVH)

typedef float f4 __attribute__((ext_vector_type(4)));

// z[b, c, t]: for each (b, j, t), channels {2j, 2j+1, 96+2j, 96+2j+1}
// (split index n = 2g + k for c = 96g + 2j + k) mixed by 4x4 W, times mask.
// Streams (x, z) are nontemporal: zero reuse, keep L2 for the mask.
__global__ __launch_bounds__(256) void invconv_z(
    const f4* __restrict__ x, const f4* __restrict__ mask,
    const float* __restrict__ w, f4* __restrict__ out)
{
    int gid = blockIdx.x * 256 + threadIdx.x;   // [0, B*CS*TVH)
    int tv  = gid & (TVH - 1);
    int bj  = gid >> 10;                        // / TVH
    int j   = bj % CS;
    int b   = bj / CS;

    // Uniform weight load (thread-invariant -> scalar loads)
    float wr[16];
#pragma unroll
    for (int i = 0; i < 16; ++i) wr[i] = w[i];

    long base = (long)b * C * TV;
    int  c0   = 2 * j;         // n = 0 pair
    int  c2   = 96 + 2 * j;    // n = 2 pair
    int  cin[4] = { c0, c0 + 1, c2, c2 + 1 };

    // 8 nontemporal loads in flight (2 t-positions x 4 channels)
    f4 a0[4], a1[4];
#pragma unroll
    for (int n = 0; n < 4; ++n) {
        const f4* p = x + base + (long)cin[n] * TV + tv;
        a0[n] = __builtin_nontemporal_load(p);
        a1[n] = __builtin_nontemporal_load(p + TVH);
    }
    f4 m0 = mask[(long)b * TV + tv];
    f4 m1 = mask[(long)b * TV + tv + TVH];

#pragma unroll
    for (int i = 0; i < 4; ++i) {
        f4 o0 = (f4)(0.f), o1 = (f4)(0.f);
#pragma unroll
        for (int n = 0; n < 4; ++n) {
            float s = wr[i * 4 + n];
            o0 += s * a0[n];
            o1 += s * a1[n];
        }
        o0 *= m0; o1 *= m1;
        f4* q = out + base + (long)cin[i] * TV + tv;
        __builtin_nontemporal_store(o0, q);
        __builtin_nontemporal_store(o1, q + TVH);
    }
}

// logdet[b] = log|det(W)| * (C/N_SPLIT) * sum(mask[b])
__global__ __launch_bounds__(256) void invconv_logdet(
    const float* __restrict__ mask, const float* __restrict__ w,
    float* __restrict__ ld)
{
    int b = blockIdx.x;
    float s = 0.f;
    for (int t = threadIdx.x; t < T; t += 256) s += mask[(long)b * T + t];
#pragma unroll
    for (int off = 32; off; off >>= 1) s += __shfl_down(s, off, 64);

    __shared__ float partial[4];
    int lane = threadIdx.x & 63, wv = threadIdx.x >> 6;
    if (lane == 0) partial[wv] = s;
    __syncthreads();

    if (threadIdx.x == 0) {
        float xlen = partial[0] + partial[1] + partial[2] + partial[3];
        double a[16];
#pragma unroll
        for (int i = 0; i < 16; ++i) a[i] = (double)w[i];
        // det(4x4) via 2x2-block cofactors in double: W ~ orthogonal so
        // log|det| ~ 0 and gets amplified by 48*8192 -> need precision.
        double s0 = a[0]*a[5]  - a[1]*a[4];
        double s1 = a[0]*a[6]  - a[2]*a[4];
        double s2 = a[0]*a[7]  - a[3]*a[4];
        double s3 = a[1]*a[6]  - a[2]*a[5];
        double s4 = a[1]*a[7]  - a[3]*a[5];
        double s5 = a[2]*a[7]  - a[3]*a[6];
        double c5 = a[10]*a[15] - a[11]*a[14];
        double c4 = a[9]*a[15]  - a[11]*a[13];
        double c3 = a[9]*a[14]  - a[10]*a[13];
        double c2 = a[8]*a[15]  - a[11]*a[12];
        double c1 = a[8]*a[14]  - a[10]*a[12];
        double c0 = a[8]*a[13]  - a[9]*a[12];
        double det = s0*c5 - s1*c4 + s2*c3 + s3*c2 - s4*c1 + s5*c0;
        ld[b] = (float)(log(fabs(det)) * (double)(C / 4) * (double)xlen);
    }
}

extern "C" void kernel_launch(void* const* d_in, const int* in_sizes, int n_in,
                              void* d_out, int out_size, void* d_ws, size_t ws_size,
                              hipStream_t stream) {
    const float* x    = (const float*)d_in[0];   // (32, 192, 8192) fp32
    const float* mask = (const float*)d_in[1];   // (32, 1, 8192) fp32
    const float* w    = (const float*)d_in[2];   // (4, 4) fp32
    float* z  = (float*)d_out;                           // 32*192*8192
    float* ld = (float*)d_out + (size_t)B * C * T;       // +32

    int total = B * CS * TVH;                    // 1,572,864 threads
    invconv_z<<<total / 256, 256, 0, stream>>>(
        (const f4*)x, (const f4*)mask, w, (f4*)z);
    invconv_logdet<<<B, 256, 0, stream>>>(mask, w, ld);
}

// Round 3
// 322.663 us; speedup vs baseline: 1.0481x; 1.0120x over previous
//
#include <hip/hip_runtime.h>
#include <math.h>

// Problem constants (fixed by setup_inputs)
#define B   32
#define C   192
#define CS  48      // C / N_SPLIT
#define T   8192
#define TV  2048    // T / 4   (float4 elements along t)
#define TVQ 512     // TV / 4  (each thread does 4 t-positions, stride TVQ)

typedef float f4 __attribute__((ext_vector_type(4)));

// z[b, c, t]: for each (b, j, t), channels {2j, 2j+1, 96+2j, 96+2j+1}
// (split index n = 2g + k for c = 96g + 2j + k) mixed by 4x4 W, times mask.
// x / z are nontemporal zero-reuse streams; mask stays cached.
__global__ __launch_bounds__(256) void invconv_z(
    const f4* __restrict__ x, const f4* __restrict__ mask,
    const float* __restrict__ w, f4* __restrict__ out)
{
    int gid = blockIdx.x * 256 + threadIdx.x;   // [0, B*CS*TVQ)
    int tv  = gid & (TVQ - 1);
    int bj  = gid >> 9;                         // / TVQ
    int j   = bj % CS;
    int b   = bj / CS;

    // Thread-invariant weight -> scalar loads (broadcast)
    float wr[16];
#pragma unroll
    for (int i = 0; i < 16; ++i) wr[i] = w[i];

    long base = (long)b * C * TV;
    int  c0   = 2 * j;         // split 0/1 pair
    int  c2   = 96 + 2 * j;    // split 2/3 pair
    int  cio[4] = { c0, c0 + 1, c2, c2 + 1 };

    // 16 nontemporal loads in flight (4 t-positions x 4 channels)
    f4 a[4][4];                 // [tpos][chan]
    const f4* p[4];
#pragma unroll
    for (int n = 0; n < 4; ++n) {
        p[n] = x + base + (long)cio[n] * TV + tv;
#pragma unroll
        for (int q = 0; q < 4; ++q)
            a[q][n] = __builtin_nontemporal_load(p[n] + q * TVQ);
    }
    const f4* mp = mask + (long)b * TV + tv;
    f4 m[4];
#pragma unroll
    for (int q = 0; q < 4; ++q) m[q] = mp[q * TVQ];

#pragma unroll
    for (int i = 0; i < 4; ++i) {
        f4* d = out + (p[i] - x);   // same offset as input channel cio[i]
#pragma unroll
        for (int q = 0; q < 4; ++q) {
            f4 o = (f4)(0.f);
#pragma unroll
            for (int n = 0; n < 4; ++n) o += wr[i * 4 + n] * a[q][n];
            o *= m[q];
            __builtin_nontemporal_store(o, d + q * TVQ);
        }
    }
}

// logdet[b] = log|det(W)| * (C/N_SPLIT) * sum(mask[b])
__global__ __launch_bounds__(512) void invconv_logdet(
    const f4* __restrict__ mask, const float* __restrict__ w,
    float* __restrict__ ld)
{
    int b = blockIdx.x;
    f4 v = mask[(long)b * TV + threadIdx.x];               // 512 thr x f4 = 2048 f4
    float s = (v.x + v.y) + (v.z + v.w);
#pragma unroll
    for (int off = 32; off; off >>= 1) s += __shfl_down(s, off, 64);

    __shared__ float partial[8];
    int lane = threadIdx.x & 63, wv = threadIdx.x >> 6;
    if (lane == 0) partial[wv] = s;
    __syncthreads();

    if (threadIdx.x == 0) {
        float xlen = 0.f;
#pragma unroll
        for (int i = 0; i < 8; ++i) xlen += partial[i];
        double a[16];
#pragma unroll
        for (int i = 0; i < 16; ++i) a[i] = (double)w[i];
        // det(4x4) via 2x2-block cofactors in double: W ~ orthogonal so
        // log|det| ~ 0 and gets amplified by 48*8192 -> need precision.
        double s0 = a[0]*a[5]  - a[1]*a[4];
        double s1 = a[0]*a[6]  - a[2]*a[4];
        double s2 = a[0]*a[7]  - a[3]*a[4];
        double s3 = a[1]*a[6]  - a[2]*a[5];
        double s4 = a[1]*a[7]  - a[3]*a[5];
        double s5 = a[2]*a[7]  - a[3]*a[6];
        double c5 = a[10]*a[15] - a[11]*a[14];
        double c4 = a[9]*a[15]  - a[11]*a[13];
        double c3 = a[9]*a[14]  - a[10]*a[13];
        double c2 = a[8]*a[15]  - a[11]*a[12];
        double c1 = a[8]*a[14]  - a[10]*a[12];
        double c0 = a[8]*a[13]  - a[9]*a[12];
        double det = s0*c5 - s1*c4 + s2*c3 + s3*c2 - s4*c1 + s5*c0;
        ld[b] = (float)(log(fabs(det)) * (double)(C / 4) * (double)xlen);
    }
}

extern "C" void kernel_launch(void* const* d_in, const int* in_sizes, int n_in,
                              void* d_out, int out_size, void* d_ws, size_t ws_size,
                              hipStream_t stream) {
    const float* x    = (const float*)d_in[0];   // (32, 192, 8192) fp32
    const float* mask = (const float*)d_in[1];   // (32, 1, 8192) fp32
    const float* w    = (const float*)d_in[2];   // (4, 4) fp32
    float* z  = (float*)d_out;                           // 32*192*8192
    float* ld = (float*)d_out + (size_t)B * C * T;       // +32

    int total = B * CS * TVQ;                    // 786,432 threads
    invconv_z<<<total / 256, 256, 0, stream>>>(
        (const f4*)x, (const f4*)mask, w, (f4*)z);
    invconv_logdet<<<B, 512, 0, stream>>>((const f4*)mask, w, ld);
}